// Round 16
// baseline (1181.184 us; speedup 1.0000x reference)
//
#include <hip/hip_runtime.h>

#define NN    16384
#define HD    128
#define G4    512
#define KST   16
#define NRELS 3
#define NPB   16   // nodes per lstm block
#define LOG2E 1.44269504f
#define TT    2.8853901f   // 2*log2(e)

using f16x8 = __attribute__((ext_vector_type(8))) _Float16;
using f32x4 = __attribute__((ext_vector_type(4))) float;

static __device__ __forceinline__ f32x4 f4splat(float v) {
    f32x4 r; r[0] = v; r[1] = v; r[2] = v; r[3] = v; return r;
}
static __device__ __forceinline__ f16x8 load8h(const float* p) {
    const float4 a = ((const float4*)p)[0];
    const float4 b = ((const float4*)p)[1];
    f16x8 r;
    r[0] = (_Float16)a.x; r[1] = (_Float16)a.y; r[2] = (_Float16)a.z; r[3] = (_Float16)a.w;
    r[4] = (_Float16)b.x; r[5] = (_Float16)b.y; r[6] = (_Float16)b.z; r[7] = (_Float16)b.w;
    return r;
}
// load 8 f32, scale by s, convert fp16 (pre-scaled gate algebra)
static __device__ __forceinline__ f16x8 load8hs(const float* p, float s) {
    const float4 a = ((const float4*)p)[0];
    const float4 b = ((const float4*)p)[1];
    f16x8 r;
    r[0] = (_Float16)(a.x * s); r[1] = (_Float16)(a.y * s);
    r[2] = (_Float16)(a.z * s); r[3] = (_Float16)(a.w * s);
    r[4] = (_Float16)(b.x * s); r[5] = (_Float16)(b.y * s);
    r[6] = (_Float16)(b.z * s); r[7] = (_Float16)(b.w * s);
    return r;
}
static __device__ __forceinline__ f32x4 mfma16h(f16x8 a, f16x8 b, f32x4 c) {
    return __builtin_amdgcn_mfma_f32_16x16x32_f16(a, b, c, 0, 0, 0);
}
static __device__ __forceinline__ unsigned short f2h_bits(float f) {
    return __builtin_bit_cast(unsigned short, (_Float16)f);
}
static __device__ __forceinline__ float h2f(unsigned short b) {
    return (float)__builtin_bit_cast(_Float16, b);
}

// ---------------------------------------------------------------------------
// C[row,col] = A[row,:] @ W[r][col,:]^T (+bias[r][col]); fp16 inputs, f32 acc.
// MODE 0: f32 out [row*OUTC+col]            (tc = conn @ trans.T)
// MODE 1: fp16 out, gate-quad packed, pre-scaled (i,f,o x log2e; g x 2log2e)
//         quad offset = (r*NN+row)*512 + (col&127)*4 + (col>>7)
// ---------------------------------------------------------------------------
template <int OUTC, int MODE>
__global__ __launch_bounds__(512, 2) void gemm_rt(
    const float* __restrict__ A, const float* __restrict__ W,
    const float* __restrict__ bias, void* __restrict__ outp)
{
    constexpr int CW = OUTC / 8;
    constexpr int CT = CW / 16;
    const int tid = threadIdx.x;
    const int w = tid >> 6, lane = tid & 63;
    const int g = lane >> 4, m = lane & 15;
    const int n0 = blockIdx.x * 64;
    const int r = blockIdx.y;
    const float* Wr = W + (size_t)r * OUTC * HD;

    f32x4 acc[4][CT];
#pragma unroll
    for (int rt = 0; rt < 4; ++rt)
#pragma unroll
        for (int ct = 0; ct < CT; ++ct) acc[rt][ct] = f4splat(0.0f);

#pragma unroll
    for (int kc = 0; kc < 4; ++kc) {
        f16x8 a[4];
#pragma unroll
        for (int rt = 0; rt < 4; ++rt)
            a[rt] = load8h(A + (size_t)(n0 + rt * 16 + m) * HD + kc * 32 + 8 * g);
        f16x8 b[CT];
#pragma unroll
        for (int ct = 0; ct < CT; ++ct)
            b[ct] = load8h(Wr + (size_t)(w * CW + ct * 16 + m) * HD + kc * 32 + 8 * g);
#pragma unroll
        for (int rt = 0; rt < 4; ++rt)
#pragma unroll
            for (int ct = 0; ct < CT; ++ct)
                acc[rt][ct] = mfma16h(a[rt], b[ct], acc[rt][ct]);
    }

#pragma unroll
    for (int rt = 0; rt < 4; ++rt)
#pragma unroll
        for (int ct = 0; ct < CT; ++ct) {
            const int col = w * CW + ct * 16 + m;
            const float bv = bias ? bias[r * OUTC + col] : 0.0f;
#pragma unroll
            for (int e = 0; e < 4; ++e) {
                const int row = n0 + rt * 16 + 4 * g + e;
                const float v = acc[rt][ct][e] + bv;
                if constexpr (MODE == 0) {
                    ((float*)outp)[(size_t)row * OUTC + col] = v;
                } else {
                    const int q = col >> 7;
                    const float s = (q == 2) ? 2.0f * LOG2E : LOG2E;
                    ((unsigned short*)outp)[((size_t)r * NN + row) * G4 + (size_t)(col & 127) * 4 + q] =
                        f2h_bits(v * s);
                }
            }
        }
}

// ---------------------------------------------------------------------------
// R14 structure with the block barrier replaced by producer/consumer FLAG
// sync: flags[w] = number of completed cell-steps by wave w (monotone).
// Wave w's MFMA k-chunk kc needs only h cols kc*32..+31 = waves 2kc,2kc+1 ->
// spin on those two flags, starting at its own chunk and round-robining.
// Waves may skew up to 1 full step (safe with the h double-buffer; proof:
// cell(t+2) is gated on all flags >= t+2, which implies every wave finished
// its step-(t+1) reads). No s_barrier in the step loop at all -> fast waves
// run their trans-heavy cell while slow waves are still in MFMA.
// 16 nodes/block, one relation; Whh resident (64 VGPR, pre-scaled);
// direct 8B gather prefetched 1 step ahead; rcp-fused exp2 cell.
// ---------------------------------------------------------------------------
__global__ __launch_bounds__(512, 4) void lstm_kernel(
    const float* __restrict__ x, const int* __restrict__ nbr,
    const float* __restrict__ Whh, const float* __restrict__ fcs,
    const float* __restrict__ fcn, const float* __restrict__ bias,
    const unsigned short* __restrict__ xW, float* __restrict__ Xout)
{
    __shared__ unsigned short h_lds[2][NPB * HD];   // fp16, swizzled, dbuf 8KB
    __shared__ int idx_lds[KST * NPB];              // [t][n], idx<<10, 1KB
    __shared__ int flags[8];                        // per-wave completed cells

    const int tid = threadIdx.x;
    const int w = tid >> 6, lane = tid & 63;
    const int g = lane >> 4, m = lane & 15;
    const int n0 = blockIdx.x * NPB;
    const int r = blockIdx.y;
    const unsigned laneoff = (unsigned)(w * 16 + m) * 8u;
    const char* xwr = (const char*)(xW + (size_t)r * NN * G4);

    if (tid < KST * NPB) {
        const int t = tid >> 4, n = tid & 15;
        idx_lds[tid] = nbr[((size_t)r * NN + n0 + n) * KST + t] << 10;
    }
    if (tid < 8) flags[tid] = 0;

    // Whh B-fragments: quads i,f,o x log2e; quad g x 2*log2e (resident)
    f16x8 bw[4][4];
    const float* whr = Whh + (size_t)r * G4 * HD;
#pragma unroll
    for (int q = 0; q < 4; ++q) {
        const float s = (q == 2) ? 2.0f * LOG2E : LOG2E;
#pragma unroll
        for (int kc = 0; kc < 4; ++kc)
            bw[q][kc] = load8hs(whr + (size_t)(q * 128 + w * 16 + m) * HD + kc * 32 + 8 * g, s);
    }

    // step-invariant LDS offsets (ushort units)
    int rd_off[4], wr_off[4];
#pragma unroll
    for (int kc = 0; kc < 4; ++kc)
        rd_off[kc] = m * HD + ((kc * 32 + 8 * g) ^ ((m & 7) << 3));
#pragma unroll
    for (int e = 0; e < 4; ++e) {
        const int row = 4 * g + e;
        wr_off[e] = row * HD + ((w * 16 + m) ^ ((row & 7) << 3));
    }

    float cst[4] = {0.0f, 0.0f, 0.0f, 0.0f};   // 2*log2e * c
    __syncthreads();   // idx_lds + flags ready (only block-wide barrier)

    // prefetch step-0 gather (4 gate-quads, 8B each)
    ushort4 xv[4];
    {
        const int4 i4 = *(const int4*)&idx_lds[4 * g];
        xv[0] = *(const ushort4*)(xwr + (unsigned)i4.x + laneoff);
        xv[1] = *(const ushort4*)(xwr + (unsigned)i4.y + laneoff);
        xv[2] = *(const ushort4*)(xwr + (unsigned)i4.z + laneoff);
        xv[3] = *(const ushort4*)(xwr + (unsigned)i4.w + laneoff);
    }

    const volatile int* vfl = (const volatile int*)flags;
    for (int t = 0; t < KST; ++t) {
        const int rb = t & 1;
        const int wb = rb ^ 1;

        // consume prefetched quads into accumulators
        f32x4 acc[4];
#pragma unroll
        for (int e = 0; e < 4; ++e) {
            acc[0][e] = h2f(xv[e].x);
            acc[1][e] = h2f(xv[e].y);
            acc[2][e] = h2f(xv[e].z);
            acc[3][e] = h2f(xv[e].w);
        }

        // prefetch next step's gather (lands under MFMA + cell)
        if (t + 1 < KST) {
            const int4 i4 = *(const int4*)&idx_lds[(t + 1) * 16 + 4 * g];
            xv[0] = *(const ushort4*)(xwr + (unsigned)i4.x + laneoff);
            xv[1] = *(const ushort4*)(xwr + (unsigned)i4.y + laneoff);
            xv[2] = *(const ushort4*)(xwr + (unsigned)i4.z + laneoff);
            xv[3] = *(const ushort4*)(xwr + (unsigned)i4.w + laneoff);
        }

        if (t > 0) {
            const unsigned short* hb = h_lds[rb];
#pragma unroll
            for (int kk = 0; kk < 4; ++kk) {
                const int kc = ((w >> 1) + kk) & 3;           // start at own chunk
                const int p0 = 2 * kc;
                // wait for the two producer waves of h cols kc*32..+31
                while (vfl[p0] < t || vfl[p0 + 1] < t) {}
                __builtin_amdgcn_sched_barrier(0);            // no hoisting past spin
                const f16x8 a = *(const f16x8*)&hb[rd_off[kc]];
#pragma unroll
                for (int q = 0; q < 4; ++q)
                    acc[q] = mfma16h(a, bw[q][kc], acc[q]);
            }
        }

        // rcp-fused LSTM cell: 5 exp2 + 2 rcp per element
        unsigned short* nh = h_lds[wb];
#pragma unroll
        for (int e = 0; e < 4; ++e) {
            const float Ai = __builtin_amdgcn_exp2f(-acc[0][e]);
            const float Af = __builtin_amdgcn_exp2f(-acc[1][e]);
            const float Ag = __builtin_amdgcn_exp2f(-acc[2][e]);
            const float Ao = __builtin_amdgcn_exp2f(-acc[3][e]);
            const float Di = 1.0f + Ai, Df = 1.0f + Af;
            const float Dg = 1.0f + Ag, Do = 1.0f + Ao;
            const float DiDg = Di * Dg;
            const float P  = __builtin_fmaf(-TT, Ag, TT);          // TT*(1-Ag)
            const float num = __builtin_fmaf(cst[e], DiDg, P * Df);
            const float R1 = __builtin_amdgcn_rcpf(Df * DiDg);
            const float csn = num * R1;                            // 2log2e*c'
            cst[e] = csn;
            const float C2 = __builtin_amdgcn_exp2f(-csn);
            const float R2 = __builtin_amdgcn_rcpf(Do * (1.0f + C2));
            nh[wr_off[e]] = f2h_bits((1.0f - C2) * R2);            // o*tanh(c')
        }
        // publish: h writes drained, then bump this wave's flag
        asm volatile("s_waitcnt lgkmcnt(0)" ::: "memory");
        if (lane == 0) ((volatile int*)flags)[w] = t + 1;
    }

    // ---- FC + leaky-relu: wait for all waves' final h, then no barrier needed
#pragma unroll
    for (int p = 0; p < 8; ++p)
        while (vfl[p] < KST) {}
    __builtin_amdgcn_sched_barrier(0);
    {
        const unsigned short* hb = h_lds[0];   // cell 15 wrote buf[(15&1)^1]=0
        const float* fsr = fcs + (size_t)r * HD * HD;
        const float* fnr = fcn + (size_t)r * HD * HD;
        const int col = w * 16 + m;
        f32x4 oacc = f4splat(bias[r * HD + col]);
#pragma unroll
        for (int kc = 0; kc < 4; ++kc) {
            const f16x8 ax = load8h(x + (size_t)(n0 + m) * HD + kc * 32 + 8 * g);
            const f16x8 ah = *(const f16x8*)&hb[rd_off[kc]];
            const f16x8 bs = load8h(fsr + (size_t)col * HD + kc * 32 + 8 * g);
            const f16x8 bn = load8h(fnr + (size_t)col * HD + kc * 32 + 8 * g);
            oacc = mfma16h(ax, bs, oacc);
            oacc = mfma16h(ah, bn, oacc);
        }
#pragma unroll
        for (int e = 0; e < 4; ++e) {
            const int row = 4 * g + e;
            float v = oacc[e];
            v = v > 0.0f ? v : 0.01f * v;
            Xout[((size_t)(n0 + row) * NRELS + r) * HD + col] = v;
        }
    }
}

// ---------------------------------------------------------------------------
// attention: one wave per node; softmax over 3 relations, f32 throughout
// ---------------------------------------------------------------------------
__global__ __launch_bounds__(256) void attn_kernel(
    const float* __restrict__ X, const float* __restrict__ tc,
    float* __restrict__ out)
{
    const int wv = blockIdx.x * (blockDim.x >> 6) + (threadIdx.x >> 6);
    const int lane = threadIdx.x & 63;
    if (wv >= NN) return;
    const size_t nb = (size_t)wv;

    const float t0 = tc[nb * HD + lane];
    const float t1 = tc[nb * HD + 64 + lane];
    float x0[3], x1[3], sc[3];
#pragma unroll
    for (int r = 0; r < 3; ++r) {
        x0[r] = X[(nb * 3 + r) * HD + lane];
        x1[r] = X[(nb * 3 + r) * HD + 64 + lane];
        float p = x0[r] * t0 + x1[r] * t1;
#pragma unroll
        for (int off = 32; off >= 1; off >>= 1)
            p += __shfl_xor(p, off, 64);
        sc[r] = p;
    }
    const float mx = fmaxf(sc[0], fmaxf(sc[1], sc[2]));
    const float e0 = __expf(sc[0] - mx), e1 = __expf(sc[1] - mx), e2 = __expf(sc[2] - mx);
    const float inv = __builtin_amdgcn_rcpf(e0 + e1 + e2);
    const float a0 = e0 * inv, a1 = e1 * inv, a2 = e2 * inv;
    out[nb * HD + lane]      = a0 * x0[0] + a1 * x0[1] + a2 * x0[2];
    out[nb * HD + 64 + lane] = a0 * x1[0] + a1 * x1[1] + a2 * x1[2];
}

extern "C" void kernel_launch(void* const* d_in, const int* in_sizes, int n_in,
                              void* d_out, int out_size, void* d_ws, size_t ws_size,
                              hipStream_t stream)
{
    const float* x     = (const float*)d_in[0];
    const float* conn  = (const float*)d_in[1];
    const int*   nbr   = (const int*)d_in[2];
    const float* trans = (const float*)d_in[3];
    const float* Wih   = (const float*)d_in[4];
    const float* Whh   = (const float*)d_in[5];
    const float* blstm = (const float*)d_in[6];
    const float* fcs   = (const float*)d_in[7];
    const float* fcn   = (const float*)d_in[8];
    const float* bias  = (const float*)d_in[9];
    float* out = (float*)d_out;

    // ws carve: xW fp16 [3][N][512] | tc f32 [N][128] | X f32 [N][3][128]
    const size_t XW_B = (size_t)NRELS * NN * G4 * 2;   //  50.3 MB
    const size_t TC_B = (size_t)NN * HD * 4;           //   8.4 MB
    const size_t XO_B = (size_t)NN * NRELS * HD * 4;   //  25.2 MB
    if (ws_size < XW_B + TC_B + XO_B) return;          //  83.9 MB floor

    char* wsb = (char*)d_ws;
    unsigned short* xW = (unsigned short*)wsb;
    float*          tc = (float*)(wsb + XW_B);
    float*          Xo = (float*)(wsb + XW_B + TC_B);

    gemm_rt<512, 1><<<dim3(NN / 64, NRELS), 512, 0, stream>>>(x, Wih, blstm, (void*)xW);
    gemm_rt<128, 0><<<dim3(NN / 64, 1), 512, 0, stream>>>(conn, trans, nullptr, (void*)tc);
    lstm_kernel<<<dim3(NN / NPB, NRELS), 512, 0, stream>>>(x, nbr, Whh, fcs, fcn, bias, xW, Xo);
    attn_kernel<<<dim3(NN / 4), 256, 0, stream>>>(Xo, tc, out);
}

// Round 17
// 314.016 us; speedup vs baseline: 3.7615x; 3.7615x over previous
//
#include <hip/hip_runtime.h>

#define NN    16384
#define HD    128
#define G4    512
#define KST   16
#define NRELS 3
#define NPB   16   // nodes per lstm block
#define LOG2E 1.44269504f
#define TT    2.8853901f   // 2*log2(e)

using f16x8 = __attribute__((ext_vector_type(8))) _Float16;
using f32x4 = __attribute__((ext_vector_type(4))) float;

static __device__ __forceinline__ f32x4 f4splat(float v) {
    f32x4 r; r[0] = v; r[1] = v; r[2] = v; r[3] = v; return r;
}
static __device__ __forceinline__ f16x8 load8h(const float* p) {
    const float4 a = ((const float4*)p)[0];
    const float4 b = ((const float4*)p)[1];
    f16x8 r;
    r[0] = (_Float16)a.x; r[1] = (_Float16)a.y; r[2] = (_Float16)a.z; r[3] = (_Float16)a.w;
    r[4] = (_Float16)b.x; r[5] = (_Float16)b.y; r[6] = (_Float16)b.z; r[7] = (_Float16)b.w;
    return r;
}
// load 8 f32, scale by s, convert fp16 (pre-scaled gate algebra)
static __device__ __forceinline__ f16x8 load8hs(const float* p, float s) {
    const float4 a = ((const float4*)p)[0];
    const float4 b = ((const float4*)p)[1];
    f16x8 r;
    r[0] = (_Float16)(a.x * s); r[1] = (_Float16)(a.y * s);
    r[2] = (_Float16)(a.z * s); r[3] = (_Float16)(a.w * s);
    r[4] = (_Float16)(b.x * s); r[5] = (_Float16)(b.y * s);
    r[6] = (_Float16)(b.z * s); r[7] = (_Float16)(b.w * s);
    return r;
}
static __device__ __forceinline__ f32x4 mfma16h(f16x8 a, f16x8 b, f32x4 c) {
    return __builtin_amdgcn_mfma_f32_16x16x32_f16(a, b, c, 0, 0, 0);
}
static __device__ __forceinline__ unsigned short f2h_bits(float f) {
    return __builtin_bit_cast(unsigned short, (_Float16)f);
}
static __device__ __forceinline__ float h2f(unsigned short b) {
    return (float)__builtin_bit_cast(_Float16, b);
}
static __device__ __forceinline__ void barrier_lgkm() {
    asm volatile("s_waitcnt lgkmcnt(0)" ::: "memory");
    __builtin_amdgcn_s_barrier();
}

// ---------------------------------------------------------------------------
// C[row,col] = A[row,:] @ W[r][col,:]^T (+bias[r][col]); fp16 inputs, f32 acc.
// MODE 0: f32 out [row*OUTC+col]            (tc = conn @ trans.T)
// MODE 1: fp16 out, gate-quad packed, pre-scaled: quads i,f,o x log2e,
//         quad g x 2*log2e (so cell uses bare exp2 with free neg modifier).
//         quad offset = (r*NN+row)*512 + (col&127)*4 + (col>>7)
// ---------------------------------------------------------------------------
template <int OUTC, int MODE>
__global__ __launch_bounds__(512, 2) void gemm_rt(
    const float* __restrict__ A, const float* __restrict__ W,
    const float* __restrict__ bias, void* __restrict__ outp)
{
    constexpr int CW = OUTC / 8;
    constexpr int CT = CW / 16;
    const int tid = threadIdx.x;
    const int w = tid >> 6, lane = tid & 63;
    const int g = lane >> 4, m = lane & 15;
    const int n0 = blockIdx.x * 64;
    const int r = blockIdx.y;
    const float* Wr = W + (size_t)r * OUTC * HD;

    f32x4 acc[4][CT];
#pragma unroll
    for (int rt = 0; rt < 4; ++rt)
#pragma unroll
        for (int ct = 0; ct < CT; ++ct) acc[rt][ct] = f4splat(0.0f);

#pragma unroll
    for (int kc = 0; kc < 4; ++kc) {
        f16x8 a[4];
#pragma unroll
        for (int rt = 0; rt < 4; ++rt)
            a[rt] = load8h(A + (size_t)(n0 + rt * 16 + m) * HD + kc * 32 + 8 * g);
        f16x8 b[CT];
#pragma unroll
        for (int ct = 0; ct < CT; ++ct)
            b[ct] = load8h(Wr + (size_t)(w * CW + ct * 16 + m) * HD + kc * 32 + 8 * g);
#pragma unroll
        for (int rt = 0; rt < 4; ++rt)
#pragma unroll
            for (int ct = 0; ct < CT; ++ct)
                acc[rt][ct] = mfma16h(a[rt], b[ct], acc[rt][ct]);
    }

#pragma unroll
    for (int rt = 0; rt < 4; ++rt)
#pragma unroll
        for (int ct = 0; ct < CT; ++ct) {
            const int col = w * CW + ct * 16 + m;
            const float bv = bias ? bias[r * OUTC + col] : 0.0f;
#pragma unroll
            for (int e = 0; e < 4; ++e) {
                const int row = n0 + rt * 16 + 4 * g + e;
                const float v = acc[rt][ct][e] + bv;
                if constexpr (MODE == 0) {
                    ((float*)outp)[(size_t)row * OUTC + col] = v;
                } else {
                    const int q = col >> 7;
                    const float s = (q == 2) ? 2.0f * LOG2E : LOG2E;
                    ((unsigned short*)outp)[((size_t)r * NN + row) * G4 + (size_t)(col & 127) * 4 + q] =
                        f2h_bits(v * s);
                }
            }
        }
}

// ---------------------------------------------------------------------------
// Champion structure (R14, 313 us measured): R12 pipeline + rcp-fused cell.
// 16 nodes/block, one relation. 8 waves; wave w owns hidden cols w*16+m for
// all 4 gate quads (Whh frags pre-scaled, 64 VGPRs, resident). Coalesced
// 2-deep gather staging via xbuf; one lgkm-only barrier/step; h dbuf
// XOR-swizzled; anti-phase-lock stagger for the (i, i+256) resident pair.
// Cell algebra: all gates as ratios over common denominators -> 5 exp2 +
// 2 rcp per element. c carried pre-scaled by 2*log2e.
// ---------------------------------------------------------------------------
__global__ __launch_bounds__(512, 4) void lstm_kernel(
    const float* __restrict__ x, const int* __restrict__ nbr,
    const float* __restrict__ Whh, const float* __restrict__ fcs,
    const float* __restrict__ fcn, const float* __restrict__ bias,
    const unsigned short* __restrict__ xW, float* __restrict__ Xout)
{
    __shared__ unsigned short h_lds[2][NPB * HD];   // fp16, swizzled, dbuf
    __shared__ unsigned short xbuf[2][NPB * G4];    // gathered quad rows, dbuf
    __shared__ int idx_lds[KST * NPB];              // [t][node], idx<<10

    const int tid = threadIdx.x;
    const int w = tid >> 6, lane = tid & 63;
    const int g = lane >> 4, m = lane & 15;
    const int n0 = blockIdx.x * NPB;
    const int r = blockIdx.y;
    const char* xwr = (const char*)(xW + (size_t)r * NN * G4);

    // anti-phase-lock: offset the (i, i+256) co-resident pair by ~half a step
    if ((blockIdx.x >> 8) & 1) {
        asm volatile("s_sleep 32");
        asm volatile("s_sleep 22");
    }

    if (tid < KST * NPB) {
        const int t = tid >> 4, n = tid & 15;
        idx_lds[tid] = nbr[((size_t)r * NN + n0 + n) * KST + t] << 10;
    }

    // Whh B-fragments: quads i,f,o x log2e; quad g x 2*log2e
    f16x8 bw[4][4];
    const float* whr = Whh + (size_t)r * G4 * HD;
#pragma unroll
    for (int q = 0; q < 4; ++q) {
        const float s = (q == 2) ? 2.0f * LOG2E : LOG2E;
#pragma unroll
        for (int kc = 0; kc < 4; ++kc)
            bw[q][kc] = load8hs(whr + (size_t)(q * 128 + w * 16 + m) * HD + kc * 32 + 8 * g, s);
    }

    // step-invariant offsets
    int rd_off[4], wr_off[4];
#pragma unroll
    for (int kc = 0; kc < 4; ++kc)
        rd_off[kc] = m * HD + ((kc * 32 + 8 * g) ^ ((m & 7) << 3));
#pragma unroll
    for (int e = 0; e < 4; ++e) {
        const int row = 4 * g + e;
        wr_off[e] = row * HD + ((w * 16 + m) ^ ((row & 7) << 3));
    }
    const int xb_wrA = (2 * w) * G4 + lane * 8;        // ushort units, 16B/lane
    const int xb_wrB = (2 * w + 1) * G4 + lane * 8;
    const int xb_rd  = (4 * g) * G4 + (w * 16 + m) * 4; // +e*G4 imm per element

    float cst[4] = {0.0f, 0.0f, 0.0f, 0.0f};   // 2*log2e * c
    __syncthreads();   // idx_lds ready

    // prologue: t=0 gather -> xbuf[0]; t=1 gather left in flight
    uint4 pa, pb;
    {
        const unsigned oa = (unsigned)idx_lds[0 * 16 + 2 * w];
        const unsigned ob = (unsigned)idx_lds[0 * 16 + 2 * w + 1];
        pa = *(const uint4*)(xwr + oa + lane * 16);
        pb = *(const uint4*)(xwr + ob + lane * 16);
        *(uint4*)&xbuf[0][xb_wrA] = pa;
        *(uint4*)&xbuf[0][xb_wrB] = pb;
        const unsigned oa1 = (unsigned)idx_lds[1 * 16 + 2 * w];
        const unsigned ob1 = (unsigned)idx_lds[1 * 16 + 2 * w + 1];
        pa = *(const uint4*)(xwr + oa1 + lane * 16);
        pb = *(const uint4*)(xwr + ob1 + lane * 16);
    }
    barrier_lgkm();

    for (int t = 0; t < KST; ++t) {
        const int rb = t & 1;        // xbuf/h read buffer
        const int wb = rb ^ 1;

        // quads for step t from xbuf (written at t-1, barrier'd)
        ushort4 xv[4];
#pragma unroll
        for (int e = 0; e < 4; ++e)
            xv[e] = *(const ushort4*)&xbuf[rb][xb_rd + e * G4];

        f32x4 acc[4];
#pragma unroll
        for (int e = 0; e < 4; ++e) {
            acc[0][e] = h2f(xv[e].x);
            acc[1][e] = h2f(xv[e].y);
            acc[2][e] = h2f(xv[e].z);
            acc[3][e] = h2f(xv[e].w);
        }

        __builtin_amdgcn_s_setprio(1);
        if (t > 0) {
            const unsigned short* hb = h_lds[rb];
#pragma unroll
            for (int kc = 0; kc < 4; ++kc) {
                const f16x8 a = *(const f16x8*)&hb[rd_off[kc]];
#pragma unroll
                for (int q = 0; q < 4; ++q)
                    acc[q] = mfma16h(a, bw[q][kc], acc[q]);
            }
        }
        __builtin_amdgcn_s_setprio(0);

        // land t+1's gather into xbuf[wb]; issue t+2's gather
        if (t + 1 < KST) {
            *(uint4*)&xbuf[wb][xb_wrA] = pa;    // waits vmcnt automatically
            *(uint4*)&xbuf[wb][xb_wrB] = pb;
            if (t + 2 < KST) {
                const unsigned oa = (unsigned)idx_lds[(t + 2) * 16 + 2 * w];
                const unsigned ob = (unsigned)idx_lds[(t + 2) * 16 + 2 * w + 1];
                pa = *(const uint4*)(xwr + oa + lane * 16);
                pb = *(const uint4*)(xwr + ob + lane * 16);
            }
        }

        // rcp-fused LSTM cell. Pre-activations arrive pre-scaled (i,f,o by
        // log2e; g by 2*log2e); cst = 2*log2e*c. Per element: 5 exp2 + 2 rcp.
        //   c' = c/Df + (1-Ag)/(Di*Dg) -> one rcp of Df*Di*Dg
        //   h  = (1-C2)/(Do*(1+C2))    -> one rcp
        unsigned short* nh = h_lds[wb];
#pragma unroll
        for (int e = 0; e < 4; ++e) {
            const float Ai = __builtin_amdgcn_exp2f(-acc[0][e]);
            const float Af = __builtin_amdgcn_exp2f(-acc[1][e]);
            const float Ag = __builtin_amdgcn_exp2f(-acc[2][e]);
            const float Ao = __builtin_amdgcn_exp2f(-acc[3][e]);
            const float Di = 1.0f + Ai, Df = 1.0f + Af;
            const float Dg = 1.0f + Ag, Do = 1.0f + Ao;
            const float DiDg = Di * Dg;
            const float P  = __builtin_fmaf(-TT, Ag, TT);          // TT*(1-Ag)
            const float num = __builtin_fmaf(cst[e], DiDg, P * Df);
            const float R1 = __builtin_amdgcn_rcpf(Df * DiDg);
            const float csn = num * R1;                            // 2*log2e*c'
            cst[e] = csn;
            const float C2 = __builtin_amdgcn_exp2f(-csn);
            const float R2 = __builtin_amdgcn_rcpf(Do * (1.0f + C2));
            nh[wr_off[e]] = f2h_bits((1.0f - C2) * R2);            // o*tanh(c')
        }
        barrier_lgkm();   // h(t) + xbuf(t+1) visible; vmcnt stays in flight
    }

    // ---- FC + leaky-relu: wave w -> out cols w*16+m, 16 nodes. h in buf[0].
    {
        const unsigned short* hb = h_lds[0];
        const float* fsr = fcs + (size_t)r * HD * HD;
        const float* fnr = fcn + (size_t)r * HD * HD;
        const int col = w * 16 + m;
        f32x4 oacc = f4splat(bias[r * HD + col]);
#pragma unroll
        for (int kc = 0; kc < 4; ++kc) {
            const f16x8 ax = load8h(x + (size_t)(n0 + m) * HD + kc * 32 + 8 * g);
            const f16x8 ah = *(const f16x8*)&hb[rd_off[kc]];
            const f16x8 bs = load8h(fsr + (size_t)col * HD + kc * 32 + 8 * g);
            const f16x8 bn = load8h(fnr + (size_t)col * HD + kc * 32 + 8 * g);
            oacc = mfma16h(ax, bs, oacc);
            oacc = mfma16h(ah, bn, oacc);
        }
#pragma unroll
        for (int e = 0; e < 4; ++e) {
            const int row = 4 * g + e;
            float v = oacc[e];
            v = v > 0.0f ? v : 0.01f * v;
            Xout[((size_t)(n0 + row) * NRELS + r) * HD + col] = v;
        }
    }
}

// ---------------------------------------------------------------------------
// attention: one wave per node; softmax over 3 relations, f32 throughout
// ---------------------------------------------------------------------------
__global__ __launch_bounds__(256) void attn_kernel(
    const float* __restrict__ X, const float* __restrict__ tc,
    float* __restrict__ out)
{
    const int wv = blockIdx.x * (blockDim.x >> 6) + (threadIdx.x >> 6);
    const int lane = threadIdx.x & 63;
    if (wv >= NN) return;
    const size_t nb = (size_t)wv;

    const float t0 = tc[nb * HD + lane];
    const float t1 = tc[nb * HD + 64 + lane];
    float x0[3], x1[3], sc[3];
#pragma unroll
    for (int r = 0; r < 3; ++r) {
        x0[r] = X[(nb * 3 + r) * HD + lane];
        x1[r] = X[(nb * 3 + r) * HD + 64 + lane];
        float p = x0[r] * t0 + x1[r] * t1;
#pragma unroll
        for (int off = 32; off >= 1; off >>= 1)
            p += __shfl_xor(p, off, 64);
        sc[r] = p;
    }
    const float mx = fmaxf(sc[0], fmaxf(sc[1], sc[2]));
    const float e0 = __expf(sc[0] - mx), e1 = __expf(sc[1] - mx), e2 = __expf(sc[2] - mx);
    const float inv = __builtin_amdgcn_rcpf(e0 + e1 + e2);
    const float a0 = e0 * inv, a1 = e1 * inv, a2 = e2 * inv;
    out[nb * HD + lane]      = a0 * x0[0] + a1 * x0[1] + a2 * x0[2];
    out[nb * HD + 64 + lane] = a0 * x1[0] + a1 * x1[1] + a2 * x1[2];
}

extern "C" void kernel_launch(void* const* d_in, const int* in_sizes, int n_in,
                              void* d_out, int out_size, void* d_ws, size_t ws_size,
                              hipStream_t stream)
{
    const float* x     = (const float*)d_in[0];
    const float* conn  = (const float*)d_in[1];
    const int*   nbr   = (const int*)d_in[2];
    const float* trans = (const float*)d_in[3];
    const float* Wih   = (const float*)d_in[4];
    const float* Whh   = (const float*)d_in[5];
    const float* blstm = (const float*)d_in[6];
    const float* fcs   = (const float*)d_in[7];
    const float* fcn   = (const float*)d_in[8];
    const float* bias  = (const float*)d_in[9];
    float* out = (float*)d_out;

    // ws carve: xW fp16 [3][N][512] | tc f32 [N][128] | X f32 [N][3][128]
    const size_t XW_B = (size_t)NRELS * NN * G4 * 2;   //  50.3 MB
    const size_t TC_B = (size_t)NN * HD * 4;           //   8.4 MB
    const size_t XO_B = (size_t)NN * NRELS * HD * 4;   //  25.2 MB
    if (ws_size < XW_B + TC_B + XO_B) return;          //  83.9 MB floor

    char* wsb = (char*)d_ws;
    unsigned short* xW = (unsigned short*)wsb;
    float*          tc = (float*)(wsb + XW_B);
    float*          Xo = (float*)(wsb + XW_B + TC_B);

    gemm_rt<512, 1><<<dim3(NN / 64, NRELS), 512, 0, stream>>>(x, Wih, blstm, (void*)xW);
    gemm_rt<128, 0><<<dim3(NN / 64, 1), 512, 0, stream>>>(conn, trans, nullptr, (void*)tc);
    lstm_kernel<<<dim3(NN / NPB, NRELS), 512, 0, stream>>>(x, nbr, Whh, fcs, fcn, bias, xW, Xo);
    attn_kernel<<<dim3(NN / 4), 256, 0, stream>>>(Xo, tc, out);
}